// Round 2
// baseline (336.969 us; speedup 1.0000x reference)
//
#include <hip/hip_runtime.h>
#include <math.h>

#define N_NODES 4096
#define H 64
#define NE 24576
#define KNN 15

// ---------------- init: zero degree counters ----------------
__global__ void k_init(int* degR, int* degC) {
    int i = blockIdx.x * blockDim.x + threadIdx.x;
    if (i < N_NODES) { degR[i] = 0; degC[i] = 0; }
}

// ---------------- histogram of original edges ----------------
__global__ void k_hist(const int* __restrict__ edges, int* degR, int* degC) {
    int e = blockIdx.x * blockDim.x + threadIdx.x;
    if (e < NE) {
        atomicAdd(&degR[edges[e]], 1);
        atomicAdd(&degC[edges[NE + e]], 1);
    }
}

// ---------------- exclusive scan (one block) -> rowptr/colptr + cursors ----------------
__global__ __launch_bounds__(1024) void k_scan(const int* __restrict__ degR, const int* __restrict__ degC,
                                               int* rowptr, int* colptr, int* cursR, int* cursC) {
    __shared__ int buf[1024];
    int t = threadIdx.x;
    for (int which = 0; which < 2; ++which) {
        const int* deg = which ? degC : degR;
        int* ptr  = which ? colptr : rowptr;
        int* curs = which ? cursC : cursR;
        int base = t * 4;
        int v0 = deg[base], v1 = deg[base + 1], v2 = deg[base + 2], v3 = deg[base + 3];
        int s = v0 + v1 + v2 + v3;
        buf[t] = s;
        __syncthreads();
        int acc = s;
        for (int o = 1; o < 1024; o <<= 1) {
            int other = (t >= o) ? buf[t - o] : 0;
            __syncthreads();
            acc += other;
            buf[t] = acc;
            __syncthreads();
        }
        int excl = acc - s;
        ptr[base]     = excl;
        ptr[base + 1] = excl + v0;
        ptr[base + 2] = excl + v0 + v1;
        ptr[base + 3] = excl + v0 + v1 + v2;
        curs[base]     = excl;
        curs[base + 1] = excl + v0;
        curs[base + 2] = excl + v0 + v1;
        curs[base + 3] = excl + v0 + v1 + v2;
        if (t == 1023) ptr[N_NODES] = acc;
        __syncthreads();
    }
}

// ---------------- scatter edge ids into CSR (by r) and CSC (by c) ----------------
__global__ void k_scatter(const int* __restrict__ edges, int* cursR, int* cursC, int* eidR, int* eidC) {
    int e = blockIdx.x * blockDim.x + threadIdx.x;
    if (e < NE) {
        int r = edges[e], c = edges[NE + e];
        int p = atomicAdd(&cursR[r], 1); eidR[p] = e;
        int q = atomicAdd(&cursC[c], 1); eidC[q] = e;
    }
}

// ---------------- kNN: 1 wave per node, per-lane register top-15 + LDS merge ----------------
__global__ __launch_bounds__(64) void k_knn(const float* __restrict__ x, int* __restrict__ knn_idx) {
    int i = blockIdx.x;
    int lane = threadIdx.x;
    float xi0 = x[i * 3 + 0], xi1 = x[i * 3 + 1], xi2 = x[i * 3 + 2];
    float sqi = xi0 * xi0 + xi1 * xi1 + xi2 * xi2;

    float dlist[KNN]; int ilist[KNN];
#pragma unroll
    for (int t = 0; t < KNN; ++t) { dlist[t] = INFINITY; ilist[t] = -1; }

    for (int j = lane; j < N_NODES; j += 64) {
        if (j == i) continue;
        float y0 = x[j * 3 + 0], y1 = x[j * 3 + 1], y2 = x[j * 3 + 2];
        float sqj = y0 * y0 + y1 * y1 + y2 * y2;
        float dot = xi0 * y0 + xi1 * y1 + xi2 * y2;
        float d = sqi + sqj - 2.0f * dot;
        if (d < dlist[KNN - 1]) {
            dlist[KNN - 1] = d; ilist[KNN - 1] = j;
#pragma unroll
            for (int t = KNN - 1; t > 0; --t) {
                if (dlist[t] < dlist[t - 1]) {
                    float td = dlist[t]; dlist[t] = dlist[t - 1]; dlist[t - 1] = td;
                    int ti = ilist[t]; ilist[t] = ilist[t - 1]; ilist[t - 1] = ti;
                }
            }
        }
    }

    __shared__ float ld[64 * KNN];
    __shared__ int   li[64 * KNN];
#pragma unroll
    for (int t = 0; t < KNN; ++t) { ld[lane * KNN + t] = dlist[t]; li[lane * KNN + t] = ilist[t]; }
    __syncthreads();

    for (int r = 0; r < KNN; ++r) {
        float bd = INFINITY; int bs = -1;
#pragma unroll
        for (int t = 0; t < KNN; ++t) {
            int s = lane + 64 * t;
            float v = ld[s];
            if (v < bd) { bd = v; bs = s; }
        }
#pragma unroll
        for (int o = 32; o > 0; o >>= 1) {
            float od = __shfl_xor(bd, o);
            int   os = __shfl_xor(bs, o);
            if (od < bd) { bd = od; bs = os; }
        }
        bs = __shfl(bs, 0);  // consistent winner
        if (lane == 0) {
            knn_idx[i * KNN + r] = li[bs];
            ld[bs] = INFINITY;
        }
        __syncthreads();
    }
}

// ---------------- DevConv: gather-based segment max (deterministic, no atomics) ----------------
__global__ __launch_bounds__(64) void k_agg(const float* __restrict__ x, const int* __restrict__ edges,
                                            const int* __restrict__ rowptr, const int* __restrict__ eidR,
                                            const int* __restrict__ knn_idx, const float* __restrict__ Wt,
                                            float* __restrict__ agg) {
    int i = blockIdx.x;
    int h = threadIdx.x;
    float w0 = Wt[h * 3 + 0], w1 = Wt[h * 3 + 1], w2 = Wt[h * 3 + 2];
    float xi0 = x[i * 3], xi1 = x[i * 3 + 1], xi2 = x[i * 3 + 2];
    float m = -INFINITY;
    int s0 = rowptr[i], s1 = rowptr[i + 1];
    for (int s = s0; s < s1; ++s) {
        int e = eidR[s];
        int c = edges[NE + e];
        float d0 = x[c * 3] - xi0, d1 = x[c * 3 + 1] - xi1, d2 = x[c * 3 + 2] - xi2;
        float v = w0 * d0 + w1 * d1 + w2 * d2;
        m = fmaxf(m, v);
    }
    for (int t = 0; t < KNN; ++t) {
        int c = knn_idx[i * KNN + t];
        float d0 = x[c * 3] - xi0, d1 = x[c * 3 + 1] - xi1, d2 = x[c * 3 + 2] - xi2;
        float v = w0 * d0 + w1 * d1 + w2 * d2;
        m = fmaxf(m, v);
    }
    if (!(m > -INFINITY)) m = 0.0f;  // matches where(isfinite, agg, 0)
    agg[i * H + h] = m;
}

// ---------------- feat = agg@Wp.T ; q = feat@Wq.T ; k = feat@Wk.T (fused per row) ----------------
__global__ __launch_bounds__(64) void k_feat_qk(const float* __restrict__ agg, const float* __restrict__ Wp,
                                                const float* __restrict__ Wq, const float* __restrict__ Wk,
                                                float* __restrict__ qb, float* __restrict__ kb) {
    int i = blockIdx.x; int h = threadIdx.x;
    __shared__ float arow[H];
    __shared__ float frow[H];
    arow[h] = agg[i * H + h];
    __syncthreads();
    float f = 0.f;
    for (int k2 = 0; k2 < H; ++k2) f += Wp[h * H + k2] * arow[k2];
    frow[h] = f;
    __syncthreads();
    float qv = 0.f, kv = 0.f;
    for (int k2 = 0; k2 < H; ++k2) {
        float fr = frow[k2];
        qv += Wq[h * H + k2] * fr;
        kv += Wk[h * H + k2] * fr;
    }
    qb[i * H + h] = qv;
    kb[i * H + h] = kv;
}

// ---------------- attention scores: 1 wave per original edge ----------------
__global__ __launch_bounds__(256) void k_att(const int* __restrict__ edges, const float* __restrict__ qb,
                                             const float* __restrict__ kb, float* __restrict__ att) {
    int wid = (blockIdx.x * blockDim.x + threadIdx.x) >> 6;
    int lane = threadIdx.x & 63;
    if (wid >= NE) return;
    int r = edges[wid], c = edges[NE + wid];
    float v = qb[r * H + lane] * kb[c * H + lane];
#pragma unroll
    for (int o = 32; o > 0; o >>= 1) v += __shfl_xor(v, o);
    if (lane == 0) att[wid] = v;
}

// ---------------- segment softmax: 1 thread per node ----------------
__global__ void k_softmax(const int* __restrict__ rowptr, const int* __restrict__ eidR,
                          const float* __restrict__ att, float* __restrict__ attn) {
    int i = blockIdx.x * blockDim.x + threadIdx.x;
    if (i >= N_NODES) return;
    int s0 = rowptr[i], s1 = rowptr[i + 1];
    float m = -INFINITY;
    for (int s = s0; s < s1; ++s) m = fmaxf(m, att[eidR[s]]);
    float den = 0.f;
    for (int s = s0; s < s1; ++s) den += expf(att[eidR[s]] - m);
    for (int s = s0; s < s1; ++s) { int e = eidR[s]; attn[e] = expf(att[e] - m) / den; }
}

// ---------------- zero-fill the 64 MB output (pure write stream) ----------------
__global__ __launch_bounds__(256) void k_zero(float* __restrict__ out) {
    int i = blockIdx.x * blockDim.x + threadIdx.x;
    float4 z = {0.f, 0.f, 0.f, 0.f};
    float4* o = (float4*)out;
    const int n4 = (N_NODES * N_NODES) / 4;
    for (int j = i; j < n4; j += gridDim.x * blockDim.x) o[j] = z;
}

// ---------------- final scatter: one wave per S-edge e1=(r,c) ----------------
// out[r, j] += attn[e1] * (count over A-edges (c,c2)) * attn[e3=(j,c2)]
// Leaves {(e2,e3)} are walked uniformly by the wave; leaf idx round-robins lanes.
__global__ __launch_bounds__(256) void k_out(const int* __restrict__ edges,
                                             const int* __restrict__ rowptr, const int* __restrict__ eidR,
                                             const int* __restrict__ colptr, const int* __restrict__ eidC,
                                             const float* __restrict__ attn, float* __restrict__ out) {
    int wid = (blockIdx.x * blockDim.x + threadIdx.x) >> 6;
    int lane = threadIdx.x & 63;
    if (wid >= NE) return;
    int r = edges[wid];
    int c = edges[NE + wid];
    float sv = attn[wid];
    float* orow = out + (size_t)r * N_NODES;
    int a0 = rowptr[c], a1 = rowptr[c + 1];
    int idx = 0;
    for (int a = a0; a < a1; ++a) {
        int e2 = eidR[a];
        int c2 = edges[NE + e2];
        int b0 = colptr[c2], b1 = colptr[c2 + 1];
        for (int b = b0; b < b1; ++b) {
            if ((idx & 63) == lane) {
                int e3 = eidC[b];
                int j = edges[e3];
                atomicAdd(&orow[j], sv * attn[e3]);
            }
            ++idx;
        }
    }
}

extern "C" void kernel_launch(void* const* d_in, const int* in_sizes, int n_in,
                              void* d_out, int out_size, void* d_ws, size_t ws_size,
                              hipStream_t stream) {
    const float* x    = (const float*)d_in[0];
    const int* edges  = (const int*)d_in[1];
    const float* Wt   = (const float*)d_in[2];
    const float* Wp   = (const float*)d_in[3];
    const float* Wq   = (const float*)d_in[4];
    const float* Wk   = (const float*)d_in[5];
    float* out = (float*)d_out;

    char* w = (char*)d_ws;
    size_t off = 0;
    auto alloc = [&](size_t bytes) -> void* {
        void* p = w + off;
        off += (bytes + 255) & ~(size_t)255;
        return p;
    };
    int*   knn    = (int*)  alloc((size_t)N_NODES * KNN * 4);
    float* agg    = (float*)alloc((size_t)N_NODES * H * 4);
    float* qb     = (float*)alloc((size_t)N_NODES * H * 4);
    float* kb     = (float*)alloc((size_t)N_NODES * H * 4);
    float* att    = (float*)alloc((size_t)NE * 4);
    float* attn   = (float*)alloc((size_t)NE * 4);
    int*   degR   = (int*)  alloc((size_t)N_NODES * 4);
    int*   degC   = (int*)  alloc((size_t)N_NODES * 4);
    int*   rowptr = (int*)  alloc((size_t)(N_NODES + 1) * 4);
    int*   colptr = (int*)  alloc((size_t)(N_NODES + 1) * 4);
    int*   cursR  = (int*)  alloc((size_t)N_NODES * 4);
    int*   cursC  = (int*)  alloc((size_t)N_NODES * 4);
    int*   eidR   = (int*)  alloc((size_t)NE * 4);
    int*   eidC   = (int*)  alloc((size_t)NE * 4);

    k_init<<<(N_NODES + 255) / 256, 256, 0, stream>>>(degR, degC);
    k_hist<<<(NE + 255) / 256, 256, 0, stream>>>(edges, degR, degC);
    k_knn<<<N_NODES, 64, 0, stream>>>(x, knn);
    k_scan<<<1, 1024, 0, stream>>>(degR, degC, rowptr, colptr, cursR, cursC);
    k_scatter<<<(NE + 255) / 256, 256, 0, stream>>>(edges, cursR, cursC, eidR, eidC);
    k_agg<<<N_NODES, 64, 0, stream>>>(x, edges, rowptr, eidR, knn, Wt, agg);
    k_feat_qk<<<N_NODES, 64, 0, stream>>>(agg, Wp, Wq, Wk, qb, kb);
    k_att<<<(NE * 64) / 256, 256, 0, stream>>>(edges, qb, kb, att);
    k_softmax<<<(N_NODES + 255) / 256, 256, 0, stream>>>(rowptr, eidR, att, attn);
    k_zero<<<2048, 256, 0, stream>>>(out);
    k_out<<<(NE * 64) / 256, 256, 0, stream>>>(edges, rowptr, eidR, colptr, eidC, attn, out);
}

// Round 3
// 225.964 us; speedup vs baseline: 1.4912x; 1.4912x over previous
//
#include <hip/hip_runtime.h>
#include <math.h>

#define N_NODES 4096
#define H 64
#define NE 24576
#define KNN 15
#define MAXPAIRS 262144

// ---------------- init: zero degree counters ----------------
__global__ void k_init(int* degR, int* degC) {
    int i = blockIdx.x * blockDim.x + threadIdx.x;
    if (i < N_NODES) { degR[i] = 0; degC[i] = 0; }
}

// ---------------- histogram of original edges ----------------
__global__ void k_hist(const int* __restrict__ edges, int* degR, int* degC) {
    int e = blockIdx.x * blockDim.x + threadIdx.x;
    if (e < NE) {
        atomicAdd(&degR[edges[e]], 1);
        atomicAdd(&degC[edges[NE + e]], 1);
    }
}

// ---------------- exclusive scan (one block) -> rowptr/colptr + cursors ----------------
__global__ __launch_bounds__(1024) void k_scan(const int* __restrict__ degR, const int* __restrict__ degC,
                                               int* rowptr, int* colptr, int* cursR, int* cursC) {
    __shared__ int buf[1024];
    int t = threadIdx.x;
    for (int which = 0; which < 2; ++which) {
        const int* deg = which ? degC : degR;
        int* ptr  = which ? colptr : rowptr;
        int* curs = which ? cursC : cursR;
        int base = t * 4;
        int v0 = deg[base], v1 = deg[base + 1], v2 = deg[base + 2], v3 = deg[base + 3];
        int s = v0 + v1 + v2 + v3;
        buf[t] = s;
        __syncthreads();
        int acc = s;
        for (int o = 1; o < 1024; o <<= 1) {
            int other = (t >= o) ? buf[t - o] : 0;
            __syncthreads();
            acc += other;
            buf[t] = acc;
            __syncthreads();
        }
        int excl = acc - s;
        ptr[base]     = excl;
        ptr[base + 1] = excl + v0;
        ptr[base + 2] = excl + v0 + v1;
        ptr[base + 3] = excl + v0 + v1 + v2;
        curs[base]     = excl;
        curs[base + 1] = excl + v0;
        curs[base + 2] = excl + v0 + v1;
        curs[base + 3] = excl + v0 + v1 + v2;
        if (t == 1023) ptr[N_NODES] = acc;
        __syncthreads();
    }
}

// ---------------- scatter edge ids into CSR/CSC + pair counts ----------------
__global__ void k_scatter(const int* __restrict__ edges, const int* __restrict__ rowptr,
                          int* cursR, int* cursC, int* eidR, int* eidC, int* pcnt) {
    int e = blockIdx.x * blockDim.x + threadIdx.x;
    if (e < NE) {
        int r = edges[e], c = edges[NE + e];
        int p = atomicAdd(&cursR[r], 1); eidR[p] = e;
        int q = atomicAdd(&cursC[c], 1); eidC[q] = e;
        pcnt[e] = rowptr[c + 1] - rowptr[c];   // A-row fan-out of this S-edge's col
    }
}

// ---------------- scan of pair counts (one block, 1024 x 24) ----------------
__global__ __launch_bounds__(1024) void k_pscan(const int* __restrict__ pcnt, int* __restrict__ poff) {
    __shared__ int buf[1024];
    int t = threadIdx.x;
    int v[24];
    int s = 0;
    int base = t * 24;
#pragma unroll
    for (int k2 = 0; k2 < 24; ++k2) { v[k2] = pcnt[base + k2]; s += v[k2]; }
    buf[t] = s;
    __syncthreads();
    int acc = s;
    for (int o = 1; o < 1024; o <<= 1) {
        int other = (t >= o) ? buf[t - o] : 0;
        __syncthreads();
        acc += other;
        buf[t] = acc;
        __syncthreads();
    }
    int run = acc - s;  // exclusive
#pragma unroll
    for (int k2 = 0; k2 < 24; ++k2) { poff[base + k2] = run; run += v[k2]; }
    if (t == 1023) poff[NE] = run;
}

// ---------------- fill pairs: thread per S-edge ----------------
__global__ void k_pfill(const int* __restrict__ edges, const int* __restrict__ rowptr,
                        const int* __restrict__ eidR, const int* __restrict__ poff,
                        const float* __restrict__ attn,
                        int* __restrict__ pairR, int* __restrict__ pairC2, float* __restrict__ pairSV) {
    int e1 = blockIdx.x * blockDim.x + threadIdx.x;
    if (e1 >= NE) return;
    int r = edges[e1];
    int c = edges[NE + e1];
    float sv = attn[e1];
    int o = poff[e1];
    int a0 = rowptr[c], a1 = rowptr[c + 1];
    for (int a = a0; a < a1; ++a) {
        int e2 = eidR[a];
        int c2 = edges[NE + e2];
        pairR[o] = r; pairC2[o] = c2; pairSV[o] = sv;
        ++o;
    }
}

// ---------------- scatter: thread per pair, loop S-col(c2) ----------------
__global__ __launch_bounds__(256) void k_pair_scatter(const int* __restrict__ edges,
                                                      const int* __restrict__ colptr, const int* __restrict__ eidC,
                                                      const int* __restrict__ poff,
                                                      const int* __restrict__ pairR, const int* __restrict__ pairC2,
                                                      const float* __restrict__ pairSV,
                                                      const float* __restrict__ attn, float* __restrict__ out) {
    int npairs = poff[NE];
    for (int p = blockIdx.x * blockDim.x + threadIdx.x; p < npairs; p += gridDim.x * blockDim.x) {
        int r = pairR[p];
        int c2 = pairC2[p];
        float sv = pairSV[p];
        float* orow = out + (size_t)r * N_NODES;
        int b0 = colptr[c2], b1 = colptr[c2 + 1];
        for (int b = b0; b < b1; ++b) {
            int e3 = eidC[b];
            int j = edges[e3];
            atomicAdd(&orow[j], sv * attn[e3]);
        }
    }
}

// ---------------- kNN: 1 wave per node, per-lane register top-15 + LDS merge ----------------
__global__ __launch_bounds__(64) void k_knn(const float* __restrict__ x, int* __restrict__ knn_idx) {
    int i = blockIdx.x;
    int lane = threadIdx.x;
    float xi0 = x[i * 3 + 0], xi1 = x[i * 3 + 1], xi2 = x[i * 3 + 2];
    float sqi = xi0 * xi0 + xi1 * xi1 + xi2 * xi2;

    float dlist[KNN]; int ilist[KNN];
#pragma unroll
    for (int t = 0; t < KNN; ++t) { dlist[t] = INFINITY; ilist[t] = -1; }

    for (int j = lane; j < N_NODES; j += 64) {
        if (j == i) continue;
        float y0 = x[j * 3 + 0], y1 = x[j * 3 + 1], y2 = x[j * 3 + 2];
        float sqj = y0 * y0 + y1 * y1 + y2 * y2;
        float dot = xi0 * y0 + xi1 * y1 + xi2 * y2;
        float d = sqi + sqj - 2.0f * dot;
        if (d < dlist[KNN - 1]) {
            dlist[KNN - 1] = d; ilist[KNN - 1] = j;
#pragma unroll
            for (int t = KNN - 1; t > 0; --t) {
                if (dlist[t] < dlist[t - 1]) {
                    float td = dlist[t]; dlist[t] = dlist[t - 1]; dlist[t - 1] = td;
                    int ti = ilist[t]; ilist[t] = ilist[t - 1]; ilist[t - 1] = ti;
                }
            }
        }
    }

    __shared__ float ld[64 * KNN];
    __shared__ int   li[64 * KNN];
#pragma unroll
    for (int t = 0; t < KNN; ++t) { ld[lane * KNN + t] = dlist[t]; li[lane * KNN + t] = ilist[t]; }
    __syncthreads();

    for (int r = 0; r < KNN; ++r) {
        float bd = INFINITY; int bs = -1;
#pragma unroll
        for (int t = 0; t < KNN; ++t) {
            int s = lane + 64 * t;
            float v = ld[s];
            if (v < bd) { bd = v; bs = s; }
        }
#pragma unroll
        for (int o = 32; o > 0; o >>= 1) {
            float od = __shfl_xor(bd, o);
            int   os = __shfl_xor(bs, o);
            if (od < bd) { bd = od; bs = os; }
        }
        bs = __shfl(bs, 0);  // consistent winner
        if (lane == 0) {
            knn_idx[i * KNN + r] = li[bs];
            ld[bs] = INFINITY;
        }
        __syncthreads();
    }
}

// ---------------- DevConv: gather-based segment max (deterministic, no atomics) ----------------
__global__ __launch_bounds__(64) void k_agg(const float* __restrict__ x, const int* __restrict__ edges,
                                            const int* __restrict__ rowptr, const int* __restrict__ eidR,
                                            const int* __restrict__ knn_idx, const float* __restrict__ Wt,
                                            float* __restrict__ agg) {
    int i = blockIdx.x;
    int h = threadIdx.x;
    float w0 = Wt[h * 3 + 0], w1 = Wt[h * 3 + 1], w2 = Wt[h * 3 + 2];
    float xi0 = x[i * 3], xi1 = x[i * 3 + 1], xi2 = x[i * 3 + 2];
    float m = -INFINITY;
    int s0 = rowptr[i], s1 = rowptr[i + 1];
    for (int s = s0; s < s1; ++s) {
        int e = eidR[s];
        int c = edges[NE + e];
        float d0 = x[c * 3] - xi0, d1 = x[c * 3 + 1] - xi1, d2 = x[c * 3 + 2] - xi2;
        float v = w0 * d0 + w1 * d1 + w2 * d2;
        m = fmaxf(m, v);
    }
    for (int t = 0; t < KNN; ++t) {
        int c = knn_idx[i * KNN + t];
        float d0 = x[c * 3] - xi0, d1 = x[c * 3 + 1] - xi1, d2 = x[c * 3 + 2] - xi2;
        float v = w0 * d0 + w1 * d1 + w2 * d2;
        m = fmaxf(m, v);
    }
    if (!(m > -INFINITY)) m = 0.0f;  // matches where(isfinite, agg, 0)
    agg[i * H + h] = m;
}

// ---------------- feat = agg@Wp.T ; q = feat@Wq.T ; k = feat@Wk.T (fused per row) ----------------
__global__ __launch_bounds__(64) void k_feat_qk(const float* __restrict__ agg, const float* __restrict__ Wp,
                                                const float* __restrict__ Wq, const float* __restrict__ Wk,
                                                float* __restrict__ qb, float* __restrict__ kb) {
    int i = blockIdx.x; int h = threadIdx.x;
    __shared__ float arow[H];
    __shared__ float frow[H];
    arow[h] = agg[i * H + h];
    __syncthreads();
    float f = 0.f;
    for (int k2 = 0; k2 < H; ++k2) f += Wp[h * H + k2] * arow[k2];
    frow[h] = f;
    __syncthreads();
    float qv = 0.f, kv = 0.f;
    for (int k2 = 0; k2 < H; ++k2) {
        float fr = frow[k2];
        qv += Wq[h * H + k2] * fr;
        kv += Wk[h * H + k2] * fr;
    }
    qb[i * H + h] = qv;
    kb[i * H + h] = kv;
}

// ---------------- attention scores: 1 wave per original edge ----------------
__global__ __launch_bounds__(256) void k_att(const int* __restrict__ edges, const float* __restrict__ qb,
                                             const float* __restrict__ kb, float* __restrict__ att) {
    int wid = (blockIdx.x * blockDim.x + threadIdx.x) >> 6;
    int lane = threadIdx.x & 63;
    if (wid >= NE) return;
    int r = edges[wid], c = edges[NE + wid];
    float v = qb[r * H + lane] * kb[c * H + lane];
#pragma unroll
    for (int o = 32; o > 0; o >>= 1) v += __shfl_xor(v, o);
    if (lane == 0) att[wid] = v;
}

// ---------------- segment softmax: 1 thread per node ----------------
__global__ void k_softmax(const int* __restrict__ rowptr, const int* __restrict__ eidR,
                          const float* __restrict__ att, float* __restrict__ attn) {
    int i = blockIdx.x * blockDim.x + threadIdx.x;
    if (i >= N_NODES) return;
    int s0 = rowptr[i], s1 = rowptr[i + 1];
    float m = -INFINITY;
    for (int s = s0; s < s1; ++s) m = fmaxf(m, att[eidR[s]]);
    float den = 0.f;
    for (int s = s0; s < s1; ++s) den += expf(att[eidR[s]] - m);
    for (int s = s0; s < s1; ++s) { int e = eidR[s]; attn[e] = expf(att[e] - m) / den; }
}

// ---------------- zero-fill the 64 MB output (pure write stream) ----------------
__global__ __launch_bounds__(256) void k_zero(float* __restrict__ out) {
    int i = blockIdx.x * blockDim.x + threadIdx.x;
    float4 z = {0.f, 0.f, 0.f, 0.f};
    float4* o = (float4*)out;
    const int n4 = (N_NODES * N_NODES) / 4;
    for (int j = i; j < n4; j += gridDim.x * blockDim.x) o[j] = z;
}

extern "C" void kernel_launch(void* const* d_in, const int* in_sizes, int n_in,
                              void* d_out, int out_size, void* d_ws, size_t ws_size,
                              hipStream_t stream) {
    const float* x    = (const float*)d_in[0];
    const int* edges  = (const int*)d_in[1];
    const float* Wt   = (const float*)d_in[2];
    const float* Wp   = (const float*)d_in[3];
    const float* Wq   = (const float*)d_in[4];
    const float* Wk   = (const float*)d_in[5];
    float* out = (float*)d_out;

    char* w = (char*)d_ws;
    size_t off = 0;
    auto alloc = [&](size_t bytes) -> void* {
        void* p = w + off;
        off += (bytes + 255) & ~(size_t)255;
        return p;
    };
    int*   knn    = (int*)  alloc((size_t)N_NODES * KNN * 4);
    float* agg    = (float*)alloc((size_t)N_NODES * H * 4);
    float* qb     = (float*)alloc((size_t)N_NODES * H * 4);
    float* kb     = (float*)alloc((size_t)N_NODES * H * 4);
    float* att    = (float*)alloc((size_t)NE * 4);
    float* attn   = (float*)alloc((size_t)NE * 4);
    int*   degR   = (int*)  alloc((size_t)N_NODES * 4);
    int*   degC   = (int*)  alloc((size_t)N_NODES * 4);
    int*   rowptr = (int*)  alloc((size_t)(N_NODES + 1) * 4);
    int*   colptr = (int*)  alloc((size_t)(N_NODES + 1) * 4);
    int*   cursR  = (int*)  alloc((size_t)N_NODES * 4);
    int*   cursC  = (int*)  alloc((size_t)N_NODES * 4);
    int*   eidR   = (int*)  alloc((size_t)NE * 4);
    int*   eidC   = (int*)  alloc((size_t)NE * 4);
    int*   pcnt   = (int*)  alloc((size_t)NE * 4);
    int*   poff   = (int*)  alloc((size_t)(NE + 1) * 4);
    int*   pairR  = (int*)  alloc((size_t)MAXPAIRS * 4);
    int*   pairC2 = (int*)  alloc((size_t)MAXPAIRS * 4);
    float* pairSV = (float*)alloc((size_t)MAXPAIRS * 4);

    k_init<<<(N_NODES + 255) / 256, 256, 0, stream>>>(degR, degC);
    k_hist<<<(NE + 255) / 256, 256, 0, stream>>>(edges, degR, degC);
    k_knn<<<N_NODES, 64, 0, stream>>>(x, knn);
    k_scan<<<1, 1024, 0, stream>>>(degR, degC, rowptr, colptr, cursR, cursC);
    k_scatter<<<(NE + 255) / 256, 256, 0, stream>>>(edges, rowptr, cursR, cursC, eidR, eidC, pcnt);
    k_agg<<<N_NODES, 64, 0, stream>>>(x, edges, rowptr, eidR, knn, Wt, agg);
    k_feat_qk<<<N_NODES, 64, 0, stream>>>(agg, Wp, Wq, Wk, qb, kb);
    k_att<<<(NE * 64) / 256, 256, 0, stream>>>(edges, qb, kb, att);
    k_softmax<<<(N_NODES + 255) / 256, 256, 0, stream>>>(rowptr, eidR, att, attn);
    k_pscan<<<1, 1024, 0, stream>>>(pcnt, poff);
    k_pfill<<<(NE + 255) / 256, 256, 0, stream>>>(edges, rowptr, eidR, poff, attn, pairR, pairC2, pairSV);
    k_zero<<<2048, 256, 0, stream>>>(out);
    k_pair_scatter<<<1024, 256, 0, stream>>>(edges, colptr, eidC, poff, pairR, pairC2, pairSV, attn, out);
}

// Round 4
// 203.428 us; speedup vs baseline: 1.6564x; 1.1108x over previous
//
#include <hip/hip_runtime.h>
#include <math.h>

#define N_NODES 4096
#define H 64
#define NE 24576
#define KNN 15

// ---------------- zero out + deg counters, build xp = (x,y,z,|x|^2) ----------------
__global__ __launch_bounds__(256) void k_zero_init(float* __restrict__ out, int* __restrict__ degR,
                                                   int* __restrict__ degC, const float* __restrict__ x,
                                                   float4* __restrict__ xp) {
    int tid = blockIdx.x * 256 + threadIdx.x;
    if (tid < N_NODES) {
        degR[tid] = 0; degC[tid] = 0;
        float a = x[tid * 3], b = x[tid * 3 + 1], c = x[tid * 3 + 2];
        xp[tid] = make_float4(a, b, c, a * a + b * b + c * c);
    }
    float4 z = {0.f, 0.f, 0.f, 0.f};
    float4* o = (float4*)out;
    const int n4 = (N_NODES * N_NODES) / 4;
    int stride = gridDim.x * 256;
    for (int j = tid; j < n4; j += stride) o[j] = z;
}

// ---------------- histogram of original edges ----------------
__global__ void k_hist(const int* __restrict__ edges, int* degR, int* degC) {
    int e = blockIdx.x * blockDim.x + threadIdx.x;
    if (e < NE) {
        atomicAdd(&degR[edges[e]], 1);
        atomicAdd(&degC[edges[NE + e]], 1);
    }
}

// ---------------- barrier-free scan: wave0 -> rowptr/cursR, wave1 -> colptr/cursC ----------------
__global__ __launch_bounds__(128) void k_scan2(const int* __restrict__ degR, const int* __restrict__ degC,
                                               int* rowptr, int* colptr, int* cursR, int* cursC) {
    int w = threadIdx.x >> 6, lane = threadIdx.x & 63;
    const int* deg = w ? degC : degR;
    int* ptr  = w ? colptr : rowptr;
    int* curs = w ? cursC : cursR;
    const int4* d4 = (const int4*)deg + lane * 16;
    int4 v[16];
    int s = 0;
#pragma unroll
    for (int t = 0; t < 16; ++t) { v[t] = d4[t]; s += v[t].x + v[t].y + v[t].z + v[t].w; }
    int incl = s;
#pragma unroll
    for (int o = 1; o < 64; o <<= 1) { int u = __shfl_up(incl, o); if (lane >= o) incl += u; }
    int run = incl - s;
    int4* p4 = (int4*)ptr + lane * 16;
    int4* c4 = (int4*)curs + lane * 16;
#pragma unroll
    for (int t = 0; t < 16; ++t) {
        int4 o;
        o.x = run; run += v[t].x;
        o.y = run; run += v[t].y;
        o.z = run; run += v[t].z;
        o.w = run; run += v[t].w;
        p4[t] = o; c4[t] = o;
    }
    if (lane == 63) ptr[N_NODES] = run;
}

// ---------------- scatter edge ids into CSR (by r) and CSC (by c) ----------------
__global__ void k_scatter(const int* __restrict__ edges, int* cursR, int* cursC, int* eidR, int* eidC) {
    int e = blockIdx.x * blockDim.x + threadIdx.x;
    if (e < NE) {
        int r = edges[e], c = edges[NE + e];
        int p = atomicAdd(&cursR[r], 1); eidR[p] = e;
        int q = atomicAdd(&cursC[c], 1); eidC[q] = e;
    }
}

// ---------------- kNN: wave per node, shared-threshold ballot filter + argmin compaction ----------------
__global__ __launch_bounds__(256) void k_knn(const float4* __restrict__ xp, int* __restrict__ knn_idx) {
    __shared__ float cd[4][128];
    __shared__ int   ci[4][128];
    int w = threadIdx.x >> 6;
    int lane = threadIdx.x & 63;
    int i = blockIdx.x * 4 + w;
    float4 pi = xp[i];
    float tau = INFINITY;
    int cnt = 0;
    float wd = INFINITY; int wi = 0;   // lane r (<15) holds r-th winner after compact

    auto compact = [&]() {
        __builtin_amdgcn_wave_barrier();
        float v0 = (lane < cnt) ? cd[w][lane] : INFINITY;
        float v1 = (lane + 64 < cnt) ? cd[w][lane + 64] : INFINITY;
        int i0 = (lane < cnt) ? ci[w][lane] : 0;
        int i1 = (lane + 64 < cnt) ? ci[w][lane + 64] : 0;
        float lastbd = INFINITY;
        for (int r = 0; r < KNN; ++r) {
            float bd; int bs;
            if (v0 <= v1) { bd = v0; bs = lane; } else { bd = v1; bs = lane + 64; }
#pragma unroll
            for (int o = 32; o > 0; o >>= 1) {
                float od = __shfl_xor(bd, o);
                int   os = __shfl_xor(bs, o);
                if (od < bd || (od == bd && os < bs)) { bd = od; bs = os; }
            }
            int own = bs & 63;
            int cand0 = __shfl(i0, own);
            int cand1 = __shfl(i1, own);
            int widx = (bs < 64) ? cand0 : cand1;
            if (lane == r) { wd = bd; wi = widx; }
            if (lane == own) { if (bs < 64) v0 = INFINITY; else v1 = INFINITY; }
            lastbd = bd;
        }
        if (lane < KNN) { cd[w][lane] = wd; ci[w][lane] = wi; }
        cnt = KNN;
        tau = lastbd;                  // 15th smallest so far (wave-uniform)
        __builtin_amdgcn_wave_barrier();
    };

    for (int iter = 0; iter < N_NODES / 64; ++iter) {
        int j = iter * 64 + lane;
        float4 pj = xp[j];
        float dot = pi.x * pj.x + pi.y * pj.y + pi.z * pj.z;
        float d = pi.w + pj.w - 2.0f * dot;
        bool pred = (d < tau) && (j != i);
        unsigned long long mask = __ballot(pred);
        if (mask) {
            int before = __popcll(mask & ((1ull << lane) - 1ull));
            if (pred) { cd[w][cnt + before] = d; ci[w][cnt + before] = j; }
            cnt += __popcll(mask);
            if (cnt > 64) compact();   // capacity 128, max 64 appends/iter -> never overflows
        }
    }
    compact();
    if (lane < KNN) knn_idx[i * KNN + lane] = wi;
}

// ---------------- DevConv max-agg + Wp/Wq/Wk (fused, block = 1 wave per node) ----------------
__global__ __launch_bounds__(64) void k_agg_feat_qk(const float4* __restrict__ xp, const int* __restrict__ edges,
                                                    const int* __restrict__ rowptr, const int* __restrict__ eidR,
                                                    const int* __restrict__ knn_idx, const float* __restrict__ Wt,
                                                    const float* __restrict__ Wp, const float* __restrict__ Wq,
                                                    const float* __restrict__ Wk,
                                                    float* __restrict__ qb, float* __restrict__ kb) {
    int i = blockIdx.x, h = threadIdx.x;
    __shared__ float mrow[H], frow[H];
    float w0 = Wt[h * 3], w1 = Wt[h * 3 + 1], w2 = Wt[h * 3 + 2];
    float4 pi = xp[i];
    float m = -INFINITY;
    int s0 = rowptr[i], s1 = rowptr[i + 1];
    for (int s = s0; s < s1; ++s) {
        int e = eidR[s];
        float4 pj = xp[edges[NE + e]];
        m = fmaxf(m, w0 * (pj.x - pi.x) + w1 * (pj.y - pi.y) + w2 * (pj.z - pi.z));
    }
    for (int t = 0; t < KNN; ++t) {
        float4 pj = xp[knn_idx[i * KNN + t]];
        m = fmaxf(m, w0 * (pj.x - pi.x) + w1 * (pj.y - pi.y) + w2 * (pj.z - pi.z));
    }
    if (!(m > -INFINITY)) m = 0.0f;
    mrow[h] = m;
    __syncthreads();
    float f = 0.f;
    for (int k2 = 0; k2 < H; ++k2) f += Wp[h * H + k2] * mrow[k2];
    frow[h] = f;
    __syncthreads();
    float qv = 0.f, kv = 0.f;
    for (int k2 = 0; k2 < H; ++k2) {
        float fr = frow[k2];
        qv += Wq[h * H + k2] * fr;
        kv += Wk[h * H + k2] * fr;
    }
    qb[i * H + h] = qv;
    kb[i * H + h] = kv;
}

// ---------------- attention scores: 1 wave per original edge ----------------
__global__ __launch_bounds__(256) void k_att(const int* __restrict__ edges, const float* __restrict__ qb,
                                             const float* __restrict__ kb, float* __restrict__ att) {
    int wid = (blockIdx.x * blockDim.x + threadIdx.x) >> 6;
    int lane = threadIdx.x & 63;
    if (wid >= NE) return;
    int r = edges[wid], c = edges[NE + wid];
    float v = qb[r * H + lane] * kb[c * H + lane];
#pragma unroll
    for (int o = 32; o > 0; o >>= 1) v += __shfl_xor(v, o);
    if (lane == 0) att[wid] = v;
}

// ---------------- segment softmax: 1 thread per node ----------------
__global__ void k_softmax(const int* __restrict__ rowptr, const int* __restrict__ eidR,
                          const float* __restrict__ att, float* __restrict__ attn) {
    int i = blockIdx.x * blockDim.x + threadIdx.x;
    if (i >= N_NODES) return;
    int s0 = rowptr[i], s1 = rowptr[i + 1];
    float m = -INFINITY;
    for (int s = s0; s < s1; ++s) m = fmaxf(m, att[eidR[s]]);
    float den = 0.f;
    for (int s = s0; s < s1; ++s) den += expf(att[eidR[s]] - m);
    for (int s = s0; s < s1; ++s) { int e = eidR[s]; attn[e] = expf(att[e] - m) / den; }
}

// ---------------- final scatter: thread = (S-edge e1, fan-slot s), s strides A-row(c) ----------------
__global__ __launch_bounds__(256) void k_pair2(const int* __restrict__ edges,
                                               const int* __restrict__ rowptr, const int* __restrict__ eidR,
                                               const int* __restrict__ colptr, const int* __restrict__ eidC,
                                               const float* __restrict__ attn, float* __restrict__ out) {
    int tid = blockIdx.x * 256 + threadIdx.x;
    int e1 = tid >> 5, s = tid & 31;
    if (e1 >= NE) return;
    int c = edges[NE + e1];
    int a0 = rowptr[c], a1 = rowptr[c + 1];
    if (a0 + s >= a1) return;
    int r = edges[e1];
    float sv = attn[e1];
    float* orow = out + (size_t)r * N_NODES;
    for (int a = a0 + s; a < a1; a += 32) {
        int e2 = eidR[a];
        int c2 = edges[NE + e2];
        int b0 = colptr[c2], b1 = colptr[c2 + 1];
        for (int b = b0; b < b1; ++b) {
            int e3 = eidC[b];
            int j = edges[e3];
            atomicAdd(&orow[j], sv * attn[e3]);
        }
    }
}

extern "C" void kernel_launch(void* const* d_in, const int* in_sizes, int n_in,
                              void* d_out, int out_size, void* d_ws, size_t ws_size,
                              hipStream_t stream) {
    const float* x    = (const float*)d_in[0];
    const int* edges  = (const int*)d_in[1];
    const float* Wt   = (const float*)d_in[2];
    const float* Wp   = (const float*)d_in[3];
    const float* Wq   = (const float*)d_in[4];
    const float* Wk   = (const float*)d_in[5];
    float* out = (float*)d_out;

    char* w = (char*)d_ws;
    size_t off = 0;
    auto alloc = [&](size_t bytes) -> void* {
        void* p = w + off;
        off += (bytes + 255) & ~(size_t)255;
        return p;
    };
    float4* xp    = (float4*)alloc((size_t)N_NODES * 16);
    int*   knn    = (int*)  alloc((size_t)N_NODES * KNN * 4);
    float* qb     = (float*)alloc((size_t)N_NODES * H * 4);
    float* kb     = (float*)alloc((size_t)N_NODES * H * 4);
    float* att    = (float*)alloc((size_t)NE * 4);
    float* attn   = (float*)alloc((size_t)NE * 4);
    int*   degR   = (int*)  alloc((size_t)N_NODES * 4);
    int*   degC   = (int*)  alloc((size_t)N_NODES * 4);
    int*   rowptr = (int*)  alloc((size_t)(N_NODES + 4) * 4);
    int*   colptr = (int*)  alloc((size_t)(N_NODES + 4) * 4);
    int*   cursR  = (int*)  alloc((size_t)N_NODES * 4);
    int*   cursC  = (int*)  alloc((size_t)N_NODES * 4);
    int*   eidR   = (int*)  alloc((size_t)NE * 4);
    int*   eidC   = (int*)  alloc((size_t)NE * 4);

    k_zero_init<<<2048, 256, 0, stream>>>(out, degR, degC, x, xp);
    k_hist<<<(NE + 255) / 256, 256, 0, stream>>>(edges, degR, degC);
    k_knn<<<N_NODES / 4, 256, 0, stream>>>(xp, knn);
    k_scan2<<<1, 128, 0, stream>>>(degR, degC, rowptr, colptr, cursR, cursC);
    k_scatter<<<(NE + 255) / 256, 256, 0, stream>>>(edges, cursR, cursC, eidR, eidC);
    k_agg_feat_qk<<<N_NODES, 64, 0, stream>>>(xp, edges, rowptr, eidR, knn, Wt, Wp, Wq, Wk, qb, kb);
    k_att<<<(NE * 64) / 256, 256, 0, stream>>>(edges, qb, kb, att);
    k_softmax<<<(N_NODES + 255) / 256, 256, 0, stream>>>(rowptr, eidR, att, attn);
    k_pair2<<<(NE * 32) / 256, 256, 0, stream>>>(edges, rowptr, eidR, colptr, eidC, attn, out);
}